// Round 2
// baseline (532.921 us; speedup 1.0000x reference)
//
#include <hip/hip_runtime.h>
#include <hip/hip_bf16.h>

typedef __attribute__((ext_vector_type(8))) short bf16x8;
typedef __attribute__((ext_vector_type(4))) float f32x4;
typedef __attribute__((ext_vector_type(4))) float vf4;
typedef __attribute__((ext_vector_type(4))) short s16x4;

__device__ __forceinline__ unsigned short f2bf(float f) {
  __hip_bfloat16 h = __float2bfloat16(f);
  union { __hip_bfloat16 h; unsigned short u; } cv; cv.h = h; return cv.u;
}

// ---------------------------------------------------------------- FPS ------
// One block per batch. Coords + running dist in registers (16 pts/thread),
// xyz mirrored in LDS for centroid broadcast. Tie-break = lowest index
// (matches np.argmax first-occurrence). __f*_rn blocks FMA contraction so
// fp32 arithmetic matches the numpy reference ((dx*dx+dy*dy)+dz*dz).
__global__ __launch_bounds__(512) void fps_kernel(const float* __restrict__ pts_g,
                                                  float* __restrict__ new_xyz) {
  __shared__ float P[8192 * 3];
  __shared__ float redD[8];
  __shared__ int   redI[8];
  __shared__ int   sFar;
  const int b = blockIdx.x, t = threadIdx.x;
  const float* src = pts_g + (size_t)b * 8192 * 3;
  float px[16], py[16], pz[16], dist[16];
#pragma unroll
  for (int k = 0; k < 16; ++k) {
    const int p = t + (k << 9);
    const float x = src[p * 3 + 0], y = src[p * 3 + 1], z = src[p * 3 + 2];
    px[k] = x; py[k] = y; pz[k] = z; dist[k] = 1e10f;
    P[p * 3 + 0] = x; P[p * 3 + 1] = y; P[p * 3 + 2] = z;
  }
  __syncthreads();
  int far = 0;
  for (int it = 0; it < 128; ++it) {
    const float cx = P[far * 3 + 0], cy = P[far * 3 + 1], cz = P[far * 3 + 2];
    if (t == 0) {
      float* o = new_xyz + ((size_t)b * 128 + it) * 3;
      o[0] = cx; o[1] = cy; o[2] = cz;
    }
    float bd = -1.f; int bi = 0x7fffffff;
#pragma unroll
    for (int k = 0; k < 16; ++k) {
      const float dx = px[k] - cx, dy = py[k] - cy, dz = pz[k] - cz;
      const float d = __fadd_rn(__fadd_rn(__fmul_rn(dx, dx), __fmul_rn(dy, dy)),
                                __fmul_rn(dz, dz));
      const float dk = fminf(dist[k], d);
      dist[k] = dk;
      if (dk > bd) { bd = dk; bi = t + (k << 9); }
    }
#pragma unroll
    for (int off = 32; off; off >>= 1) {
      const float od = __shfl_xor(bd, off);
      const int   oi = __shfl_xor(bi, off);
      if (od > bd || (od == bd && oi < bi)) { bd = od; bi = oi; }
    }
    if ((t & 63) == 0) { redD[t >> 6] = bd; redI[t >> 6] = bi; }
    __syncthreads();
    if (t == 0) {
      float md = redD[0]; int mi = redI[0];
      for (int w = 1; w < 8; ++w) {
        const float od = redD[w]; const int oi = redI[w];
        if (od > md || (od == md && oi < mi)) { md = od; mi = oi; }
      }
      sFar = mi;
    }
    __syncthreads();
    far = sFar;
  }
}

// ------------------------------------------------- pos-enc first layer -----
// H1[row=b*128+sg][j] = relu((w1[j,:]*xyz + b1[j])*s1[j] + t1[j]), fp32.
__global__ __launch_bounds__(256) void posenc_h1(const float* __restrict__ nx,
                                                 const float* __restrict__ w1,
                                                 const float* __restrict__ b1,
                                                 const float* __restrict__ s1,
                                                 const float* __restrict__ t1,
                                                 float* __restrict__ H1) {
  const int gid = blockIdx.x * 256 + threadIdx.x;
  const int row = gid >> 7, j = gid & 127;
  const float x = nx[row * 3 + 0], y = nx[row * 3 + 1], z = nx[row * 3 + 2];
  float v = w1[j * 3 + 0] * x + w1[j * 3 + 1] * y + w1[j * 3 + 2] * z + b1[j];
  v = fmaxf(fmaf(v, s1[j], t1[j]), 0.f);
  H1[gid] = v;
}

// ------------------------------------------------------- grouped GEMM ------
// 5 groups: 4 conv (M={6272,6272,4096,4096},K=1024) -> bf16 h buffers,
// 1 pos-enc (M=16384,K=128) -> fp32 directly into d_out. N=512 for all.
// 128x128 tile, BK=64, 4 waves (2x2), 16x16x32 bf16 MFMA, fp32->bf16
// reg-staged LDS. Epilogue: relu((acc + cb)*sc + sh).
struct GArgs {
  const float *A0, *A1, *A2, *A3, *A4;
  const float *W0, *W1, *W2, *W3, *W4;
  const float *c0, *c1, *c2, *c3, *c4;
  const float *s0, *s1, *s2, *s3, *s4;
  const float *t0, *t1, *t2, *t3, *t4;
  unsigned short *H0, *H1, *H2, *H3;
  float *out;
};

__global__ __launch_bounds__(256) void gemm_grouped(GArgs ga) {
  __shared__ __align__(16) unsigned short As[128][64];
  __shared__ __align__(16) unsigned short Bs[128][64];
  const int bid = blockIdx.x;
  int g, lid;
  if (bid < 196)      { g = 0; lid = bid; }
  else if (bid < 392) { g = 1; lid = bid - 196; }
  else if (bid < 520) { g = 2; lid = bid - 392; }
  else if (bid < 648) { g = 3; lid = bid - 520; }
  else                { g = 4; lid = bid - 648; }
  const float *A, *W, *cbp, *scp, *shp; unsigned short* H = nullptr;
  int K, nk;
  switch (g) {
    case 0: A=ga.A0; W=ga.W0; cbp=ga.c0; scp=ga.s0; shp=ga.t0; H=ga.H0; K=1024; nk=16; break;
    case 1: A=ga.A1; W=ga.W1; cbp=ga.c1; scp=ga.s1; shp=ga.t1; H=ga.H1; K=1024; nk=16; break;
    case 2: A=ga.A2; W=ga.W2; cbp=ga.c2; scp=ga.s2; shp=ga.t2; H=ga.H2; K=1024; nk=16; break;
    case 3: A=ga.A3; W=ga.W3; cbp=ga.c3; scp=ga.s3; shp=ga.t3; H=ga.H3; K=1024; nk=16; break;
    default:A=ga.A4; W=ga.W4; cbp=ga.c4; scp=ga.s4; shp=ga.t4; H=nullptr; K=128; nk=2; break;
  }
  const int mtile = lid >> 2, ntile = lid & 3;
  const int t = threadIdx.x, lane = t & 63, wv = t >> 6;
  const int wr = wv >> 1, wc = wv & 1;

  const float* Ap = A + (size_t)(mtile * 128 + (t >> 4)) * K + ((t & 15) << 2);
  const float* Wp = W + (size_t)(ntile * 128 + (t >> 4)) * K + ((t & 15) << 2);
  const int sRow = t >> 4;
  const int sCol = (t & 15) << 2;

  f32x4 acc[4][4];
#pragma unroll
  for (int i = 0; i < 4; ++i)
#pragma unroll
    for (int j = 0; j < 4; ++j)
      acc[i][j] = (f32x4){0.f, 0.f, 0.f, 0.f};

  for (int ks = 0; ks < nk; ++ks) {
    __syncthreads();
#pragma unroll
    for (int p = 0; p < 8; ++p) {
      const vf4 av = *(const vf4*)(Ap + (size_t)(p * 16) * K);
      const vf4 wvv = *(const vf4*)(Wp + (size_t)(p * 16) * K);
      s16x4 a4, w4;
      a4[0] = (short)f2bf(av[0]); a4[1] = (short)f2bf(av[1]);
      a4[2] = (short)f2bf(av[2]); a4[3] = (short)f2bf(av[3]);
      w4[0] = (short)f2bf(wvv[0]); w4[1] = (short)f2bf(wvv[1]);
      w4[2] = (short)f2bf(wvv[2]); w4[3] = (short)f2bf(wvv[3]);
      *(s16x4*)&As[sRow + p * 16][sCol] = a4;
      *(s16x4*)&Bs[sRow + p * 16][sCol] = w4;
    }
    __syncthreads();
#pragma unroll
    for (int kk = 0; kk < 2; ++kk) {
      const int kb = (kk << 5) + ((lane >> 4) << 3);
      bf16x8 af[4], bfr[4];
#pragma unroll
      for (int i = 0; i < 4; ++i) {
        af[i]  = *(const bf16x8*)&As[wr * 64 + i * 16 + (lane & 15)][kb];
        bfr[i] = *(const bf16x8*)&Bs[wc * 64 + i * 16 + (lane & 15)][kb];
      }
#pragma unroll
      for (int i = 0; i < 4; ++i)
#pragma unroll
        for (int j = 0; j < 4; ++j)
          acc[i][j] = __builtin_amdgcn_mfma_f32_16x16x32_bf16(af[i], bfr[j], acc[i][j], 0, 0, 0);
    }
    Ap += 64; Wp += 64;
  }

  const int mbase = mtile * 128 + wr * 64;
  const int nbase = ntile * 128 + wc * 64;
#pragma unroll
  for (int j = 0; j < 4; ++j) {
    const int col = nbase + j * 16 + (lane & 15);
    const float cbv = cbp[col], scv = scp[col], shv = shp[col];
#pragma unroll
    for (int i = 0; i < 4; ++i) {
#pragma unroll
      for (int q = 0; q < 4; ++q) {
        const int row = mbase + i * 16 + ((lane >> 4) << 2) + q;
        float v = acc[i][j][q];
        v = fmaxf(fmaf(v + cbv, scv, shv), 0.f);
        if (g < 4) H[(size_t)row * 512 + col] = f2bf(v);
        else       ga.out[(size_t)row * 512 + col] = v;
      }
    }
  }
}

// ------------------------------------------------------- mix + add ---------
// Block = (b, mod). Stage h slab [L][512] (bf16->f32) + lw in LDS; each
// thread owns one o and 32 s-accumulators; RMW-add onto pos in d_out.
struct MArgs {
  const unsigned short *H0, *H1, *H2, *H3;
  const float *lw0, *lw1, *lw2, *lw3;
  const float *lb0, *lb1, *lb2, *lb3;
  float* out;
};

__global__ __launch_bounds__(512) void mix_add(MArgs ma) {
  __shared__ float hs[49 * 512];
  __shared__ float lws[32 * 49];
  __shared__ float lbs[32];
  const int b = blockIdx.x >> 2, mod = blockIdx.x & 3, t = threadIdx.x;
  const unsigned short* H; const float* lw; const float* lb; int L;
  switch (mod) {
    case 0: H = ma.H0; lw = ma.lw0; lb = ma.lb0; L = 49; break;
    case 1: H = ma.H1; lw = ma.lw1; lb = ma.lb1; L = 49; break;
    case 2: H = ma.H2; lw = ma.lw2; lb = ma.lb2; L = 32; break;
    default:H = ma.H3; lw = ma.lw3; lb = ma.lb3; L = 32; break;
  }
  H += (size_t)b * L * 512;
  for (int i = t; i < L * 512; i += 512) hs[i] = __uint_as_float(((unsigned)H[i]) << 16);
  for (int i = t; i < 32 * L; i += 512) lws[i] = lw[i];
  if (t < 32) lbs[t] = lb[t];
  __syncthreads();
  float acc[32];
#pragma unroll
  for (int s = 0; s < 32; ++s) acc[s] = 0.f;
  for (int l = 0; l < L; ++l) {
    const float hv = hs[l * 512 + t];
#pragma unroll
    for (int s = 0; s < 32; ++s) acc[s] = fmaf(hv, lws[s * L + l], acc[s]);
  }
  float* O = ma.out + ((size_t)(b * 128 + mod * 32)) * 512 + t;
#pragma unroll
  for (int s = 0; s < 32; ++s) {
    O[(size_t)s * 512] += fmaxf(acc[s] + lbs[s], 0.f);
  }
}

// ---------------------------------------------------------------- launch ---
extern "C" void kernel_launch(void* const* d_in, const int* in_sizes, int n_in,
                              void* d_out, int out_size, void* d_ws, size_t ws_size,
                              hipStream_t stream) {
  const float* rgb    = (const float*)d_in[0];
  const float* depth  = (const float*)d_in[1];
  const float* mmw    = (const float*)d_in[2];
  const float* lidf   = (const float*)d_in[3];
  const float* pts    = (const float*)d_in[4];

  const float* cw[4]  = { (const float*)d_in[5],  (const float*)d_in[11],
                          (const float*)d_in[17], (const float*)d_in[23] };
  const float* cb[4]  = { (const float*)d_in[6],  (const float*)d_in[12],
                          (const float*)d_in[18], (const float*)d_in[24] };
  const float* bns[4] = { (const float*)d_in[7],  (const float*)d_in[13],
                          (const float*)d_in[19], (const float*)d_in[25] };
  const float* bnb[4] = { (const float*)d_in[8],  (const float*)d_in[14],
                          (const float*)d_in[20], (const float*)d_in[26] };
  const float* lw[4]  = { (const float*)d_in[9],  (const float*)d_in[15],
                          (const float*)d_in[21], (const float*)d_in[27] };
  const float* lb[4]  = { (const float*)d_in[10], (const float*)d_in[16],
                          (const float*)d_in[22], (const float*)d_in[28] };

  const float* pe_w1 = (const float*)d_in[29];
  const float* pe_b1 = (const float*)d_in[30];
  const float* pe_s1 = (const float*)d_in[31];
  const float* pe_t1 = (const float*)d_in[32];
  const float* pe_w2 = (const float*)d_in[33];
  const float* pe_b2 = (const float*)d_in[34];
  const float* pe_s2 = (const float*)d_in[35];
  const float* pe_t2 = (const float*)d_in[36];

  char* ws = (char*)d_ws;
  float* new_xyz = (float*)ws;                                   // 49152 f32
  float* H1f     = (float*)(ws + 196608);                        // 16384*128 f32
  unsigned short* h0 = (unsigned short*)(ws + 196608 + 8388608); // 6272*512 bf16
  unsigned short* h1 = h0 + (size_t)6272 * 512;
  unsigned short* h2 = h1 + (size_t)6272 * 512;                  // 4096*512
  unsigned short* h3 = h2 + (size_t)4096 * 512;
  float* out = (float*)d_out;

  fps_kernel<<<128, 512, 0, stream>>>(pts, new_xyz);
  posenc_h1<<<8192, 256, 0, stream>>>(new_xyz, pe_w1, pe_b1, pe_s1, pe_t1, H1f);

  GArgs ga;
  ga.A0 = rgb;  ga.A1 = depth; ga.A2 = mmw;  ga.A3 = lidf; ga.A4 = H1f;
  ga.W0 = cw[0]; ga.W1 = cw[1]; ga.W2 = cw[2]; ga.W3 = cw[3]; ga.W4 = pe_w2;
  ga.c0 = cb[0]; ga.c1 = cb[1]; ga.c2 = cb[2]; ga.c3 = cb[3]; ga.c4 = pe_b2;
  ga.s0 = bns[0]; ga.s1 = bns[1]; ga.s2 = bns[2]; ga.s3 = bns[3]; ga.s4 = pe_s2;
  ga.t0 = bnb[0]; ga.t1 = bnb[1]; ga.t2 = bnb[2]; ga.t3 = bnb[3]; ga.t4 = pe_t2;
  ga.H0 = h0; ga.H1 = h1; ga.H2 = h2; ga.H3 = h3;
  ga.out = out;
  gemm_grouped<<<1160, 256, 0, stream>>>(ga);

  MArgs ma;
  ma.H0 = h0; ma.H1 = h1; ma.H2 = h2; ma.H3 = h3;
  ma.lw0 = lw[0]; ma.lw1 = lw[1]; ma.lw2 = lw[2]; ma.lw3 = lw[3];
  ma.lb0 = lb[0]; ma.lb1 = lb[1]; ma.lb2 = lb[2]; ma.lb3 = lb[3];
  ma.out = out;
  mix_add<<<512, 512, 0, stream>>>(ma);
}

// Round 4
// 443.456 us; speedup vs baseline: 1.2017x; 1.2017x over previous
//
#include <hip/hip_runtime.h>
#include <hip/hip_bf16.h>

typedef __attribute__((ext_vector_type(8))) short bf16x8;
typedef __attribute__((ext_vector_type(4))) float f32x4;
typedef __attribute__((ext_vector_type(4))) float vf4;
typedef __attribute__((ext_vector_type(4))) short s16x4;
typedef __attribute__((ext_vector_type(2))) unsigned int u32x2;

__device__ __forceinline__ unsigned short f2bf(float f) {
  __hip_bfloat16 h = __float2bfloat16(f);
  union { __hip_bfloat16 h; unsigned short u; } cv; cv.h = h; return cv.u;
}

// packed fp32x4 -> bf16x4 (RNE, same bits as __float2bfloat16 per element)
__device__ __forceinline__ u32x2 cvt4(vf4 v) {
  union { __hip_bfloat162 h; unsigned u; } a, b;
  a.h = __float22bfloat162_rn(make_float2(v[0], v[1]));
  b.h = __float22bfloat162_rn(make_float2(v[2], v[3]));
  u32x2 r; r[0] = a.u; r[1] = b.u; return r;
}

// ------------------------------------------------- shared GEMM tile --------
// 128x128 tile, BK=64, 512 threads (8 waves as 2x4 -> 64x32 per wave),
// 16x16x32 bf16 MFMA, fp32->bf16 packed-cvt reg-staged LDS.
// Epilogue: relu((acc + cb)*sc + sh); H!=null -> bf16 store, else fp32 out.
__device__ __forceinline__ void gemm_tile(const float* __restrict__ A,
                                          const float* __restrict__ W,
                                          const float* __restrict__ cbp,
                                          const float* __restrict__ scp,
                                          const float* __restrict__ shp,
                                          unsigned short* __restrict__ H,
                                          float* __restrict__ out,
                                          const int K, const int nk,
                                          const int mtile, const int ntile,
                                          unsigned short (&As)[128][64],
                                          unsigned short (&Bs)[128][64]) {
  const int t = threadIdx.x, lane = t & 63, wv = t >> 6;
  const int wr = wv >> 2, wc = wv & 3;                 // 2x4 wave grid
  const float* Ap = A + (size_t)(mtile * 128 + (t >> 4)) * K + ((t & 15) << 2);
  const float* Wp = W + (size_t)(ntile * 128 + (t >> 4)) * K + ((t & 15) << 2);
  const int sRow = t >> 4;             // 0..31
  const int sCol = (t & 15) << 2;      // 0..60

  f32x4 acc[4][2];
#pragma unroll
  for (int i = 0; i < 4; ++i)
#pragma unroll
    for (int j = 0; j < 2; ++j) acc[i][j] = (f32x4){0.f, 0.f, 0.f, 0.f};

  for (int ks = 0; ks < nk; ++ks) {
    __syncthreads();
#pragma unroll
    for (int p = 0; p < 4; ++p) {
      const vf4 av  = *(const vf4*)(Ap + (size_t)(p * 32) * K);
      const vf4 wvv = *(const vf4*)(Wp + (size_t)(p * 32) * K);
      *(u32x2*)&As[sRow + p * 32][sCol] = cvt4(av);
      *(u32x2*)&Bs[sRow + p * 32][sCol] = cvt4(wvv);
    }
    __syncthreads();
#pragma unroll
    for (int kk = 0; kk < 2; ++kk) {
      const int kb = (kk << 5) + ((lane >> 4) << 3);
      bf16x8 af[4], bfv[2];
#pragma unroll
      for (int i = 0; i < 4; ++i)
        af[i] = *(const bf16x8*)&As[wr * 64 + i * 16 + (lane & 15)][kb];
#pragma unroll
      for (int j = 0; j < 2; ++j)
        bfv[j] = *(const bf16x8*)&Bs[wc * 32 + j * 16 + (lane & 15)][kb];
#pragma unroll
      for (int i = 0; i < 4; ++i)
#pragma unroll
        for (int j = 0; j < 2; ++j)
          acc[i][j] = __builtin_amdgcn_mfma_f32_16x16x32_bf16(af[i], bfv[j], acc[i][j], 0, 0, 0);
    }
    Ap += 64; Wp += 64;
  }

  const int mbase = mtile * 128 + wr * 64;
  const int nbase = ntile * 128 + wc * 32;
#pragma unroll
  for (int j = 0; j < 2; ++j) {
    const int col = nbase + j * 16 + (lane & 15);
    const float cbv = cbp[col], scv = scp[col], shv = shp[col];
#pragma unroll
    for (int i = 0; i < 4; ++i) {
#pragma unroll
      for (int q = 0; q < 4; ++q) {
        const int row = mbase + i * 16 + ((lane >> 4) << 2) + q;
        float v = acc[i][j][q];
        v = fmaxf(fmaf(v + cbv, scv, shv), 0.f);
        if (H) H[(size_t)row * 512 + col] = f2bf(v);
        else   out[(size_t)row * 512 + col] = v;
      }
    }
  }
}

// ------------------------------------------------------ fused FPS+GEMM -----
// Blocks 0..127: FPS (one per batch). Blocks 128..775: the 4 conv GEMMs.
// FPS: 512 thr x 16 pts in regs; u64-packed (dist,idx) argmax; ONE barrier
// per iteration (double-buffered red slots); winner coords broadcast via
// LDS (no 96KB point mirror -> GEMM occupancy preserved). Arithmetic is
// bit-identical to the validated r2 kernel (__f*_rn, fminf, strict >).
struct FArgs {
  const float* A[4]; const float* W[4];
  const float* cb[4]; const float* sc[4]; const float* sh[4];
  unsigned short* H[4];
  const float* pts; float* new_xyz;
};

__global__ __launch_bounds__(512) void fused_main(FArgs fa) {
  __shared__ __align__(16) unsigned short As[128][64];
  __shared__ __align__(16) unsigned short Bs[128][64];
  __shared__ unsigned long long red[2][8];
  __shared__ float redC[2][8][3];
  const int bid = blockIdx.x;

  if (bid < 128) {
    // ------------------------------------------------------------ FPS ----
    const int t = threadIdx.x, wv = t >> 6, lane = t & 63;
    const float* src = fa.pts + (size_t)bid * 8192 * 3;
    float px[16], py[16], pz[16], dist[16];
#pragma unroll
    for (int k = 0; k < 16; ++k) {
      const int p = t + (k << 9);
      px[k] = src[p * 3 + 0]; py[k] = src[p * 3 + 1]; pz[k] = src[p * 3 + 2];
      dist[k] = 1e10f;
    }
    float cx = src[0], cy = src[1], cz = src[2];   // first farthest = idx 0
    for (int it = 0; it < 128; ++it) {
      if (t == 0) {
        float* o = fa.new_xyz + ((size_t)bid * 128 + it) * 3;
        o[0] = cx; o[1] = cy; o[2] = cz;
      }
      float bd = -1.f, bx = 0.f, by = 0.f, bz = 0.f; int bi = 0;
#pragma unroll
      for (int k = 0; k < 16; ++k) {
        const float dx = px[k] - cx, dy = py[k] - cy, dz = pz[k] - cz;
        const float d = __fadd_rn(__fadd_rn(__fmul_rn(dx, dx), __fmul_rn(dy, dy)),
                                  __fmul_rn(dz, dz));
        const float dk = fminf(dist[k], d);
        dist[k] = dk;
        if (dk > bd) { bd = dk; bi = t + (k << 9); bx = px[k]; by = py[k]; bz = pz[k]; }
      }
      // pack: d>=0 so float bits are order-monotone; tie -> min idx
      const unsigned long long myKey =
          ((unsigned long long)__float_as_uint(bd) << 13) | (unsigned)(8191 - bi);
      unsigned long long key = myKey;
#pragma unroll
      for (int off = 32; off; off >>= 1) {
        const unsigned long long o = __shfl_xor(key, off);
        key = (o > key) ? o : key;
      }
      const int p = it & 1;
      if (lane == 0) red[p][wv] = key;
      if (myKey == key) {           // exactly one lane per wave
        redC[p][wv][0] = bx; redC[p][wv][1] = by; redC[p][wv][2] = bz;
      }
      __syncthreads();
      unsigned long long m = red[p][0]; int w = 0;
#pragma unroll
      for (int i = 1; i < 8; ++i) {
        const unsigned long long v = red[p][i];
        if (v > m) { m = v; w = i; }
      }
      cx = redC[p][w][0]; cy = redC[p][w][1]; cz = redC[p][w][2];
    }
  } else {
    // ------------------------------------------------------ conv GEMMs ---
    const int cb = bid - 128;
    int g, lid;
    if (cb < 196)      { g = 0; lid = cb; }
    else if (cb < 392) { g = 1; lid = cb - 196; }
    else if (cb < 520) { g = 2; lid = cb - 392; }
    else               { g = 3; lid = cb - 520; }
    gemm_tile(fa.A[g], fa.W[g], fa.cb[g], fa.sc[g], fa.sh[g], fa.H[g], nullptr,
              1024, 16, lid >> 2, lid & 3, As, Bs);
  }
}

// ------------------------------------------------- pos-enc first layer -----
__global__ __launch_bounds__(256) void posenc_h1(const float* __restrict__ nx,
                                                 const float* __restrict__ w1,
                                                 const float* __restrict__ b1,
                                                 const float* __restrict__ s1,
                                                 const float* __restrict__ t1,
                                                 float* __restrict__ H1) {
  const int gid = blockIdx.x * 256 + threadIdx.x;
  const int row = gid >> 7, j = gid & 127;
  const float x = nx[row * 3 + 0], y = nx[row * 3 + 1], z = nx[row * 3 + 2];
  float v = w1[j * 3 + 0] * x + w1[j * 3 + 1] * y + w1[j * 3 + 2] * z + b1[j];
  v = fmaxf(fmaf(v, s1[j], t1[j]), 0.f);
  H1[gid] = v;
}

// ------------------------------------------------------ pos-enc GEMM -------
struct PArgs {
  const float *A, *W, *cb, *sc, *sh;
  float* out;
};
__global__ __launch_bounds__(512) void gemm_pe(PArgs pa) {
  __shared__ __align__(16) unsigned short As[128][64];
  __shared__ __align__(16) unsigned short Bs[128][64];
  const int lid = blockIdx.x;
  gemm_tile(pa.A, pa.W, pa.cb, pa.sc, pa.sh, nullptr, pa.out,
            128, 2, lid >> 2, lid & 3, As, Bs);
}

// ------------------------------------------------------- mix + add ---------
struct MArgs {
  const unsigned short *H0, *H1, *H2, *H3;
  const float *lw0, *lw1, *lw2, *lw3;
  const float *lb0, *lb1, *lb2, *lb3;
  float* out;
};

__global__ __launch_bounds__(512) void mix_add(MArgs ma) {
  __shared__ float hs[49 * 512];
  __shared__ float lws[32 * 49];
  __shared__ float lbs[32];
  const int b = blockIdx.x >> 2, mod = blockIdx.x & 3, t = threadIdx.x;
  const unsigned short* H; const float* lw; const float* lb; int L;
  switch (mod) {
    case 0: H = ma.H0; lw = ma.lw0; lb = ma.lb0; L = 49; break;
    case 1: H = ma.H1; lw = ma.lw1; lb = ma.lb1; L = 49; break;
    case 2: H = ma.H2; lw = ma.lw2; lb = ma.lb2; L = 32; break;
    default:H = ma.H3; lw = ma.lw3; lb = ma.lb3; L = 32; break;
  }
  H += (size_t)b * L * 512;
  for (int i = t; i < L * 512; i += 512) hs[i] = __uint_as_float(((unsigned)H[i]) << 16);
  for (int i = t; i < 32 * L; i += 512) lws[i] = lw[i];
  if (t < 32) lbs[t] = lb[t];
  __syncthreads();
  float acc[32];
#pragma unroll
  for (int s = 0; s < 32; ++s) acc[s] = 0.f;
  for (int l = 0; l < L; ++l) {
    const float hv = hs[l * 512 + t];
#pragma unroll
    for (int s = 0; s < 32; ++s) acc[s] = fmaf(hv, lws[s * L + l], acc[s]);
  }
  float* O = ma.out + ((size_t)(b * 128 + mod * 32)) * 512 + t;
#pragma unroll
  for (int s = 0; s < 32; ++s) {
    O[(size_t)s * 512] += fmaxf(acc[s] + lbs[s], 0.f);
  }
}

// ---------------------------------------------------------------- launch ---
extern "C" void kernel_launch(void* const* d_in, const int* in_sizes, int n_in,
                              void* d_out, int out_size, void* d_ws, size_t ws_size,
                              hipStream_t stream) {
  const float* rgb    = (const float*)d_in[0];
  const float* depth  = (const float*)d_in[1];
  const float* mmw    = (const float*)d_in[2];
  const float* lidf   = (const float*)d_in[3];
  const float* pts    = (const float*)d_in[4];

  const float* cw[4]  = { (const float*)d_in[5],  (const float*)d_in[11],
                          (const float*)d_in[17], (const float*)d_in[23] };
  const float* cb[4]  = { (const float*)d_in[6],  (const float*)d_in[12],
                          (const float*)d_in[18], (const float*)d_in[24] };
  const float* bns[4] = { (const float*)d_in[7],  (const float*)d_in[13],
                          (const float*)d_in[19], (const float*)d_in[25] };
  const float* bnb[4] = { (const float*)d_in[8],  (const float*)d_in[14],
                          (const float*)d_in[20], (const float*)d_in[26] };
  const float* lw[4]  = { (const float*)d_in[9],  (const float*)d_in[15],
                          (const float*)d_in[21], (const float*)d_in[27] };
  const float* lb[4]  = { (const float*)d_in[10], (const float*)d_in[16],
                          (const float*)d_in[22], (const float*)d_in[28] };

  const float* pe_w1 = (const float*)d_in[29];
  const float* pe_b1 = (const float*)d_in[30];
  const float* pe_s1 = (const float*)d_in[31];
  const float* pe_t1 = (const float*)d_in[32];
  const float* pe_w2 = (const float*)d_in[33];
  const float* pe_b2 = (const float*)d_in[34];
  const float* pe_s2 = (const float*)d_in[35];
  const float* pe_t2 = (const float*)d_in[36];

  char* ws = (char*)d_ws;
  float* new_xyz = (float*)ws;                                   // 49152 f32
  float* H1f     = (float*)(ws + 196608);                        // 16384*128 f32
  unsigned short* h0 = (unsigned short*)(ws + 196608 + 8388608); // 6272*512 bf16
  unsigned short* h1 = h0 + (size_t)6272 * 512;
  unsigned short* h2 = h1 + (size_t)6272 * 512;                  // 4096*512
  unsigned short* h3 = h2 + (size_t)4096 * 512;
  float* out = (float*)d_out;

  FArgs fa;
  for (int i = 0; i < 4; ++i) {
    fa.A[i] = (i == 0) ? rgb : (i == 1) ? depth : (i == 2) ? mmw : lidf;
    fa.W[i] = cw[i]; fa.cb[i] = cb[i]; fa.sc[i] = bns[i]; fa.sh[i] = bnb[i];
  }
  fa.H[0] = h0; fa.H[1] = h1; fa.H[2] = h2; fa.H[3] = h3;
  fa.pts = pts; fa.new_xyz = new_xyz;
  fused_main<<<776, 512, 0, stream>>>(fa);

  posenc_h1<<<8192, 256, 0, stream>>>(new_xyz, pe_w1, pe_b1, pe_s1, pe_t1, H1f);

  PArgs pa;
  pa.A = H1f; pa.W = pe_w2; pa.cb = pe_b2; pa.sc = pe_s2; pa.sh = pe_t2;
  pa.out = out;
  gemm_pe<<<512, 512, 0, stream>>>(pa);

  MArgs ma;
  ma.H0 = h0; ma.H1 = h1; ma.H2 = h2; ma.H3 = h3;
  ma.lw0 = lw[0]; ma.lw1 = lw[1]; ma.lw2 = lw[2]; ma.lw3 = lw[3];
  ma.lb0 = lb[0]; ma.lb1 = lb[1]; ma.lb2 = lb[2]; ma.lb3 = lb[3];
  ma.out = out;
  mix_add<<<512, 512, 0, stream>>>(ma);
}

// Round 6
// 419.900 us; speedup vs baseline: 1.2692x; 1.0561x over previous
//
#include <hip/hip_runtime.h>
#include <hip/hip_bf16.h>

typedef __attribute__((ext_vector_type(8))) short bf16x8;
typedef __attribute__((ext_vector_type(4))) float f32x4;
typedef __attribute__((ext_vector_type(4))) float vf4;
typedef __attribute__((ext_vector_type(2))) unsigned int u32x2;

__device__ __forceinline__ unsigned short f2bf(float f) {
  __hip_bfloat16 h = __float2bfloat16(f);
  union { __hip_bfloat16 h; unsigned short u; } cv; cv.h = h; return cv.u;
}

// packed fp32x4 -> bf16x4 (RNE, same bits as __float2bfloat16 per element)
__device__ __forceinline__ u32x2 cvt4(vf4 v) {
  union { __hip_bfloat162 h; unsigned u; } a, b;
  a.h = __float22bfloat162_rn(make_float2(v[0], v[1]));
  b.h = __float22bfloat162_rn(make_float2(v[2], v[3]));
  u32x2 r; r[0] = a.u; r[1] = b.u; return r;
}

// ------------------------------------------------- shared GEMM tile --------
// 128x128 tile, BK=64, 512 threads (8 waves as 2x4 -> 64x32 per wave),
// 16x16x32 bf16 MFMA. LDS rows padded to 72 (144B): 16-lane row-stride reads
// land 2 lanes/bank (free) instead of 16-way conflict at 64 (128B) rows.
// PE=true: A is computed on the fly from xyz (pos-enc layer-1 fused into
// staging). Epilogue: relu((acc + cb)*sc + sh); H!=null -> bf16, else fp32.
template <bool PE>
__device__ __forceinline__ void gemm_tile_t(const float* __restrict__ A,
                                            const float* __restrict__ W,
                                            const float* __restrict__ cbp,
                                            const float* __restrict__ scp,
                                            const float* __restrict__ shp,
                                            const float* __restrict__ w1,
                                            const float* __restrict__ b1,
                                            const float* __restrict__ s1,
                                            const float* __restrict__ t1,
                                            unsigned short* __restrict__ H,
                                            float* __restrict__ out,
                                            const int K, const int nk,
                                            const int mtile, const int ntile,
                                            unsigned short (&As)[128][72],
                                            unsigned short (&Bs)[128][72]) {
  const int t = threadIdx.x, lane = t & 63, wv = t >> 6;
  const int wr = wv >> 2, wc = wv & 3;                 // 2x4 wave grid
  const float* Ap = A + (size_t)(mtile * 128 + (t >> 4)) * K + ((t & 15) << 2);
  const float* Wp = W + (size_t)(ntile * 128 + (t >> 4)) * K + ((t & 15) << 2);
  const int sRow = t >> 4;             // 0..31
  const int sCol = (t & 15) << 2;      // 0..60

  f32x4 acc[4][2];
#pragma unroll
  for (int i = 0; i < 4; ++i)
#pragma unroll
    for (int j = 0; j < 2; ++j) acc[i][j] = (f32x4){0.f, 0.f, 0.f, 0.f};

  for (int ks = 0; ks < nk; ++ks) {
    __syncthreads();
#pragma unroll
    for (int p = 0; p < 4; ++p) {
      vf4 av;
      if constexpr (PE) {
        // pos-enc layer 1 fused: row = sampled point, cols = 4 channels
        const int row = mtile * 128 + sRow + p * 32;
        const float x = A[row * 3 + 0], y = A[row * 3 + 1], z = A[row * 3 + 2];
#pragma unroll
        for (int cc = 0; cc < 4; ++cc) {
          const int j = ks * 64 + sCol + cc;
          float v = w1[j * 3 + 0] * x + w1[j * 3 + 1] * y + w1[j * 3 + 2] * z + b1[j];
          av[cc] = fmaxf(fmaf(v, s1[j], t1[j]), 0.f);
        }
      } else {
        av = *(const vf4*)(Ap + (size_t)(p * 32) * K);
      }
      const vf4 wvv = *(const vf4*)(Wp + (size_t)(p * 32) * K);
      *(u32x2*)&As[sRow + p * 32][sCol] = cvt4(av);
      *(u32x2*)&Bs[sRow + p * 32][sCol] = cvt4(wvv);
    }
    __syncthreads();
#pragma unroll
    for (int kk = 0; kk < 2; ++kk) {
      const int kb = (kk << 5) + ((lane >> 4) << 3);
      bf16x8 af[4], bfv[2];
#pragma unroll
      for (int i = 0; i < 4; ++i)
        af[i] = *(const bf16x8*)&As[wr * 64 + i * 16 + (lane & 15)][kb];
#pragma unroll
      for (int j = 0; j < 2; ++j)
        bfv[j] = *(const bf16x8*)&Bs[wc * 32 + j * 16 + (lane & 15)][kb];
#pragma unroll
      for (int i = 0; i < 4; ++i)
#pragma unroll
        for (int j = 0; j < 2; ++j)
          acc[i][j] = __builtin_amdgcn_mfma_f32_16x16x32_bf16(af[i], bfv[j], acc[i][j], 0, 0, 0);
    }
    Ap += 64; Wp += 64;
  }

  const int mbase = mtile * 128 + wr * 64;
  const int nbase = ntile * 128 + wc * 32;
#pragma unroll
  for (int j = 0; j < 2; ++j) {
    const int col = nbase + j * 16 + (lane & 15);
    const float cbv = cbp[col], scv = scp[col], shv = shp[col];
#pragma unroll
    for (int i = 0; i < 4; ++i) {
#pragma unroll
      for (int q = 0; q < 4; ++q) {
        const int row = mbase + i * 16 + ((lane >> 4) << 2) + q;
        float v = acc[i][j][q];
        v = fmaxf(fmaf(v + cbv, scv, shv), 0.f);
        if (H) H[(size_t)row * 512 + col] = f2bf(v);
        else   out[(size_t)row * 512 + col] = v;
      }
    }
  }
}

// ------------------------------------------------------ fused FPS+GEMM -----
// Blocks 0..127: FPS (one per batch) at wave prio 3 (latency chain must not
// lose issue slots to co-resident GEMM waves). Blocks 128..775: conv GEMMs.
struct FArgs {
  const float* A[4]; const float* W[4];
  const float* cb[4]; const float* sc[4]; const float* sh[4];
  unsigned short* H[4];
  const float* pts; float* new_xyz;
};

__global__ __launch_bounds__(512, 2) void fused_main(FArgs fa) {
  __shared__ __align__(16) unsigned short As[128][72];
  __shared__ __align__(16) unsigned short Bs[128][72];
  __shared__ unsigned long long red[2][8];
  __shared__ float redC[2][8][3];
  const int bid = blockIdx.x;

  if (bid < 128) {
    // ------------------------------------------------------------ FPS ----
    __builtin_amdgcn_s_setprio(3);
    const int t = threadIdx.x, wv = t >> 6, lane = t & 63;
    const float* src = fa.pts + (size_t)bid * 8192 * 3;
    float px[16], py[16], pz[16], dist[16];
#pragma unroll
    for (int k = 0; k < 16; ++k) {
      const int p = t + (k << 9);
      px[k] = src[p * 3 + 0]; py[k] = src[p * 3 + 1]; pz[k] = src[p * 3 + 2];
      dist[k] = 1e10f;
    }
    float cx = src[0], cy = src[1], cz = src[2];   // first farthest = idx 0
    for (int it = 0; it < 128; ++it) {
      if (t == 0) {
        float* o = fa.new_xyz + ((size_t)bid * 128 + it) * 3;
        o[0] = cx; o[1] = cy; o[2] = cz;
      }
      float bd = -1.f, bx = 0.f, by = 0.f, bz = 0.f; int bi = 0;
#pragma unroll
      for (int k = 0; k < 16; ++k) {
        const float dx = px[k] - cx, dy = py[k] - cy, dz = pz[k] - cz;
        const float d = __fadd_rn(__fadd_rn(__fmul_rn(dx, dx), __fmul_rn(dy, dy)),
                                  __fmul_rn(dz, dz));
        const float dk = fminf(dist[k], d);
        dist[k] = dk;
        if (dk > bd) { bd = dk; bi = t + (k << 9); bx = px[k]; by = py[k]; bz = pz[k]; }
      }
      // pack: d>=0 so float bits are order-monotone; tie -> min idx
      const unsigned long long myKey =
          ((unsigned long long)__float_as_uint(bd) << 13) | (unsigned)(8191 - bi);
      unsigned long long key = myKey;
#pragma unroll
      for (int off = 32; off; off >>= 1) {
        const unsigned long long o = __shfl_xor(key, off);
        key = (o > key) ? o : key;
      }
      const int p = it & 1;
      if (lane == 0) red[p][wv] = key;
      if (myKey == key) {           // exactly one lane per wave
        redC[p][wv][0] = bx; redC[p][wv][1] = by; redC[p][wv][2] = bz;
      }
      __syncthreads();
      unsigned long long m = red[p][0]; int w = 0;
#pragma unroll
      for (int i = 1; i < 8; ++i) {
        const unsigned long long v = red[p][i];
        if (v > m) { m = v; w = i; }
      }
      cx = redC[p][w][0]; cy = redC[p][w][1]; cz = redC[p][w][2];
    }
  } else {
    // ------------------------------------------------------ conv GEMMs ---
    const int cb = bid - 128;
    int g, lid;
    if (cb < 196)      { g = 0; lid = cb; }
    else if (cb < 392) { g = 1; lid = cb - 196; }
    else if (cb < 520) { g = 2; lid = cb - 392; }
    else               { g = 3; lid = cb - 520; }
    gemm_tile_t<false>(fa.A[g], fa.W[g], fa.cb[g], fa.sc[g], fa.sh[g],
                       nullptr, nullptr, nullptr, nullptr,
                       fa.H[g], nullptr, 1024, 16, lid >> 2, lid & 3, As, Bs);
  }
}

// --------------------------------------- pos-enc (layer1 fused) GEMM -------
struct PArgs {
  const float *xyz, *w1, *b1, *s1, *t1;   // layer-1 (fused into staging)
  const float *W, *cb, *sc, *sh;          // layer-2
  float* out;
};
__global__ __launch_bounds__(512, 2) void gemm_pe(PArgs pa) {
  __shared__ __align__(16) unsigned short As[128][72];
  __shared__ __align__(16) unsigned short Bs[128][72];
  const int lid = blockIdx.x;
  gemm_tile_t<true>(pa.xyz, pa.W, pa.cb, pa.sc, pa.sh,
                    pa.w1, pa.b1, pa.s1, pa.t1,
                    nullptr, pa.out, 128, 2, lid >> 2, lid & 3, As, Bs);
}

// ------------------------------------------------------- mix + add ---------
// Block = (b, mod). Stage h slab as RAW bf16 (50KB -> 2 blocks/CU) with
// vectorized 16B copies; convert on LDS read. RMW-add onto pos in d_out.
struct MArgs {
  const unsigned short *H0, *H1, *H2, *H3;
  const float *lw0, *lw1, *lw2, *lw3;
  const float *lb0, *lb1, *lb2, *lb3;
  float* out;
};

__global__ __launch_bounds__(512) void mix_add(MArgs ma) {
  __shared__ unsigned short hsb[49 * 512];
  __shared__ float lws[32 * 49];
  __shared__ float lbs[32];
  const int b = blockIdx.x >> 2, mod = blockIdx.x & 3, t = threadIdx.x;
  const unsigned short* H; const float* lw; const float* lb; int L;
  switch (mod) {
    case 0: H = ma.H0; lw = ma.lw0; lb = ma.lb0; L = 49; break;
    case 1: H = ma.H1; lw = ma.lw1; lb = ma.lb1; L = 49; break;
    case 2: H = ma.H2; lw = ma.lw2; lb = ma.lb2; L = 32; break;
    default:H = ma.H3; lw = ma.lw3; lb = ma.lb3; L = 32; break;
  }
  H += (size_t)b * L * 512;
  const int nv = (L * 512) >> 3;           // 16B chunks (8 bf16)
  for (int i = t; i < nv; i += 512)
    *(bf16x8*)&hsb[i << 3] = *(const bf16x8*)&H[i << 3];
  for (int i = t; i < 32 * L; i += 512) lws[i] = lw[i];
  if (t < 32) lbs[t] = lb[t];
  __syncthreads();
  float acc[32];
#pragma unroll
  for (int s = 0; s < 32; ++s) acc[s] = 0.f;
  for (int l = 0; l < L; ++l) {
    const float hv = __uint_as_float(((unsigned)hsb[l * 512 + t]) << 16);
#pragma unroll
    for (int s = 0; s < 32; ++s) acc[s] = fmaf(hv, lws[s * L + l], acc[s]);
  }
  float* O = ma.out + ((size_t)(b * 128 + mod * 32)) * 512 + t;
#pragma unroll
  for (int s = 0; s < 32; ++s) {
    O[(size_t)s * 512] += fmaxf(acc[s] + lbs[s], 0.f);
  }
}

// ---------------------------------------------------------------- launch ---
extern "C" void kernel_launch(void* const* d_in, const int* in_sizes, int n_in,
                              void* d_out, int out_size, void* d_ws, size_t ws_size,
                              hipStream_t stream) {
  const float* rgb    = (const float*)d_in[0];
  const float* depth  = (const float*)d_in[1];
  const float* mmw    = (const float*)d_in[2];
  const float* lidf   = (const float*)d_in[3];
  const float* pts    = (const float*)d_in[4];

  const float* cw[4]  = { (const float*)d_in[5],  (const float*)d_in[11],
                          (const float*)d_in[17], (const float*)d_in[23] };
  const float* cb[4]  = { (const float*)d_in[6],  (const float*)d_in[12],
                          (const float*)d_in[18], (const float*)d_in[24] };
  const float* bns[4] = { (const float*)d_in[7],  (const float*)d_in[13],
                          (const float*)d_in[19], (const float*)d_in[25] };
  const float* bnb[4] = { (const float*)d_in[8],  (const float*)d_in[14],
                          (const float*)d_in[20], (const float*)d_in[26] };
  const float* lw[4]  = { (const float*)d_in[9],  (const float*)d_in[15],
                          (const float*)d_in[21], (const float*)d_in[27] };
  const float* lb[4]  = { (const float*)d_in[10], (const float*)d_in[16],
                          (const float*)d_in[22], (const float*)d_in[28] };

  const float* pe_w1 = (const float*)d_in[29];
  const float* pe_b1 = (const float*)d_in[30];
  const float* pe_s1 = (const float*)d_in[31];
  const float* pe_t1 = (const float*)d_in[32];
  const float* pe_w2 = (const float*)d_in[33];
  const float* pe_b2 = (const float*)d_in[34];
  const float* pe_s2 = (const float*)d_in[35];
  const float* pe_t2 = (const float*)d_in[36];

  char* ws = (char*)d_ws;
  float* new_xyz = (float*)ws;                                   // 49152 f32
  unsigned short* h0 = (unsigned short*)(ws + 196608);           // 6272*512 bf16
  unsigned short* h1 = h0 + (size_t)6272 * 512;
  unsigned short* h2 = h1 + (size_t)6272 * 512;                  // 4096*512
  unsigned short* h3 = h2 + (size_t)4096 * 512;
  float* out = (float*)d_out;

  FArgs fa;
  for (int i = 0; i < 4; ++i) {
    fa.A[i] = (i == 0) ? rgb : (i == 1) ? depth : (i == 2) ? mmw : lidf;
    fa.W[i] = cw[i]; fa.cb[i] = cb[i]; fa.sc[i] = bns[i]; fa.sh[i] = bnb[i];
  }
  fa.H[0] = h0; fa.H[1] = h1; fa.H[2] = h2; fa.H[3] = h3;
  fa.pts = pts; fa.new_xyz = new_xyz;
  fused_main<<<776, 512, 0, stream>>>(fa);

  PArgs pa;
  pa.xyz = new_xyz; pa.w1 = pe_w1; pa.b1 = pe_b1; pa.s1 = pe_s1; pa.t1 = pe_t1;
  pa.W = pe_w2; pa.cb = pe_b2; pa.sc = pe_s2; pa.sh = pe_t2;
  pa.out = out;
  gemm_pe<<<512, 512, 0, stream>>>(pa);

  MArgs ma;
  ma.H0 = h0; ma.H1 = h1; ma.H2 = h2; ma.H3 = h3;
  ma.lw0 = lw[0]; ma.lw1 = lw[1]; ma.lw2 = lw[2]; ma.lw3 = lw[3];
  ma.lb0 = lb[0]; ma.lb1 = lb[1]; ma.lb2 = lb[2]; ma.lb3 = lb[3];
  ma.out = out;
  mix_add<<<512, 512, 0, stream>>>(ma);
}

// Round 8
// 399.273 us; speedup vs baseline: 1.3347x; 1.0517x over previous
//
#include <hip/hip_runtime.h>
#include <hip/hip_bf16.h>

typedef __attribute__((ext_vector_type(8))) short bf16x8;
typedef __attribute__((ext_vector_type(4))) float f32x4;
typedef __attribute__((ext_vector_type(4))) float vf4;
typedef __attribute__((ext_vector_type(2))) unsigned int u32x2;
typedef __attribute__((ext_vector_type(2))) unsigned long long u64x2;

__device__ __forceinline__ unsigned short f2bf(float f) {
  __hip_bfloat16 h = __float2bfloat16(f);
  union { __hip_bfloat16 h; unsigned short u; } cv; cv.h = h; return cv.u;
}

// packed fp32x4 -> bf16x4 (RNE, same bits as __float2bfloat16 per element)
__device__ __forceinline__ u32x2 cvt4(vf4 v) {
  union { __hip_bfloat162 h; unsigned u; } a, b;
  a.h = __float22bfloat162_rn(make_float2(v[0], v[1]));
  b.h = __float22bfloat162_rn(make_float2(v[2], v[3]));
  u32x2 r; r[0] = a.u; r[1] = b.u; return r;
}

// ------------------------------------------------- shared GEMM tile --------
// 128x128 tile, BK=64, 512 threads (8 waves as 2x4 -> 64x32 per wave),
// 16x16x32 bf16 MFMA. LDS rows padded to 72 (144B): 16-lane row-stride reads
// land 2 lanes/bank (free) instead of 16-way conflict at 64 (128B) rows.
// PE=true: A is computed on the fly from xyz (pos-enc layer-1 fused into
// staging). Epilogue: relu((acc + cb)*sc + sh); H!=null -> bf16, else fp32.
template <bool PE>
__device__ __forceinline__ void gemm_tile_t(const float* __restrict__ A,
                                            const float* __restrict__ W,
                                            const float* __restrict__ cbp,
                                            const float* __restrict__ scp,
                                            const float* __restrict__ shp,
                                            const float* __restrict__ w1,
                                            const float* __restrict__ b1,
                                            const float* __restrict__ s1,
                                            const float* __restrict__ t1,
                                            unsigned short* __restrict__ H,
                                            float* __restrict__ out,
                                            const int K, const int nk,
                                            const int mtile, const int ntile,
                                            unsigned short (&As)[128][72],
                                            unsigned short (&Bs)[128][72]) {
  const int t = threadIdx.x, lane = t & 63, wv = t >> 6;
  const int wr = wv >> 2, wc = wv & 3;                 // 2x4 wave grid
  const float* Ap = A + (size_t)(mtile * 128 + (t >> 4)) * K + ((t & 15) << 2);
  const float* Wp = W + (size_t)(ntile * 128 + (t >> 4)) * K + ((t & 15) << 2);
  const int sRow = t >> 4;             // 0..31
  const int sCol = (t & 15) << 2;      // 0..60

  f32x4 acc[4][2];
#pragma unroll
  for (int i = 0; i < 4; ++i)
#pragma unroll
    for (int j = 0; j < 2; ++j) acc[i][j] = (f32x4){0.f, 0.f, 0.f, 0.f};

  for (int ks = 0; ks < nk; ++ks) {
    __syncthreads();
#pragma unroll
    for (int p = 0; p < 4; ++p) {
      vf4 av;
      if constexpr (PE) {
        // pos-enc layer 1 fused: row = sampled point, cols = 4 channels
        const int row = mtile * 128 + sRow + p * 32;
        const float x = A[row * 3 + 0], y = A[row * 3 + 1], z = A[row * 3 + 2];
#pragma unroll
        for (int cc = 0; cc < 4; ++cc) {
          const int j = ks * 64 + sCol + cc;
          float v = w1[j * 3 + 0] * x + w1[j * 3 + 1] * y + w1[j * 3 + 2] * z + b1[j];
          av[cc] = fmaxf(fmaf(v, s1[j], t1[j]), 0.f);
        }
      } else {
        av = *(const vf4*)(Ap + (size_t)(p * 32) * K);
      }
      const vf4 wvv = *(const vf4*)(Wp + (size_t)(p * 32) * K);
      *(u32x2*)&As[sRow + p * 32][sCol] = cvt4(av);
      *(u32x2*)&Bs[sRow + p * 32][sCol] = cvt4(wvv);
    }
    __syncthreads();
#pragma unroll
    for (int kk = 0; kk < 2; ++kk) {
      const int kb = (kk << 5) + ((lane >> 4) << 3);
      bf16x8 af[4], bfv[2];
#pragma unroll
      for (int i = 0; i < 4; ++i)
        af[i] = *(const bf16x8*)&As[wr * 64 + i * 16 + (lane & 15)][kb];
#pragma unroll
      for (int j = 0; j < 2; ++j)
        bfv[j] = *(const bf16x8*)&Bs[wc * 32 + j * 16 + (lane & 15)][kb];
#pragma unroll
      for (int i = 0; i < 4; ++i)
#pragma unroll
        for (int j = 0; j < 2; ++j)
          acc[i][j] = __builtin_amdgcn_mfma_f32_16x16x32_bf16(af[i], bfv[j], acc[i][j], 0, 0, 0);
    }
    Ap += 64; Wp += 64;
  }

  const int mbase = mtile * 128 + wr * 64;
  const int nbase = ntile * 128 + wc * 32;
#pragma unroll
  for (int j = 0; j < 2; ++j) {
    const int col = nbase + j * 16 + (lane & 15);
    const float cbv = cbp[col], scv = scp[col], shv = shp[col];
#pragma unroll
    for (int i = 0; i < 4; ++i) {
#pragma unroll
      for (int q = 0; q < 4; ++q) {
        const int row = mbase + i * 16 + ((lane >> 4) << 2) + q;
        float v = acc[i][j][q];
        v = fmaxf(fmaf(v + cbv, scv, shv), 0.f);
        if (H) H[(size_t)row * 512 + col] = f2bf(v);
        else   out[(size_t)row * 512 + col] = v;
      }
    }
  }
}

// ------------------------------------------------------ fused FPS+GEMM -----
// Blocks 0..127: FPS (one per batch). Blocks 128..775: the 4 conv GEMMs.
// FPS v3: inner loop tracks (dist,idx) only; winner coords re-fetched from
// pts[widx] (exact same fp32 bits, L2-hot). Centroid outputs buffered in
// LDS, bulk-written at the end (no per-iter global-store vmcnt drain at
// the barrier). One barrier/iter, double-buffered red slots, b128 scan.
struct FArgs {
  const float* A[4]; const float* W[4];
  const float* cb[4]; const float* sc[4]; const float* sh[4];
  unsigned short* H[4];
  const float* pts; float* new_xyz;
};

__global__ __attribute__((amdgpu_flat_work_group_size(512, 512),
                          amdgpu_waves_per_eu(2, 4)))
void fused_main(FArgs fa) {
  __shared__ __align__(16) unsigned short As[128][72];
  __shared__ __align__(16) unsigned short Bs[128][72];
  __shared__ __align__(16) unsigned long long red[2][8];
  __shared__ float nxb[128 * 3];
  const int bid = blockIdx.x;

  if (bid < 128) {
    // ------------------------------------------------------------ FPS ----
    __builtin_amdgcn_s_setprio(3);
    const int t = threadIdx.x, wv = t >> 6, lane = t & 63;
    const float* src = fa.pts + (size_t)bid * 8192 * 3;
    float px[16], py[16], pz[16], dist[16];
#pragma unroll
    for (int k = 0; k < 16; ++k) {
      const int p = t + (k << 9);
      px[k] = src[p * 3 + 0]; py[k] = src[p * 3 + 1]; pz[k] = src[p * 3 + 2];
      dist[k] = 1e10f;
    }
    float cx = src[0], cy = src[1], cz = src[2];   // first farthest = idx 0
    for (int it = 0; it < 128; ++it) {
      if (t == 0) {
        nxb[it * 3 + 0] = cx; nxb[it * 3 + 1] = cy; nxb[it * 3 + 2] = cz;
      }
      float bd = -1.f; int bi = 0;
#pragma unroll
      for (int k = 0; k < 16; ++k) {
        const float dx = px[k] - cx, dy = py[k] - cy, dz = pz[k] - cz;
        const float d = __fadd_rn(__fadd_rn(__fmul_rn(dx, dx), __fmul_rn(dy, dy)),
                                  __fmul_rn(dz, dz));
        const float dk = fminf(dist[k], d);
        dist[k] = dk;
        if (dk > bd) { bd = dk; bi = t + (k << 9); }
      }
      // pack: d>=0 so float bits are order-monotone; tie -> min idx
      unsigned long long key =
          ((unsigned long long)__float_as_uint(bd) << 13) | (unsigned)(8191 - bi);
#pragma unroll
      for (int off = 32; off; off >>= 1) {
        const unsigned long long o = __shfl_xor(key, off);
        key = (o > key) ? o : key;
      }
      const int p = it & 1;
      if (lane == 0) red[p][wv] = key;
      __syncthreads();
      const u64x2 r0 = *(const u64x2*)&red[p][0];
      const u64x2 r1 = *(const u64x2*)&red[p][2];
      const u64x2 r2 = *(const u64x2*)&red[p][4];
      const u64x2 r3 = *(const u64x2*)&red[p][6];
      unsigned long long a0 = r0[0] > r0[1] ? r0[0] : r0[1];
      unsigned long long a1 = r1[0] > r1[1] ? r1[0] : r1[1];
      unsigned long long a2 = r2[0] > r2[1] ? r2[0] : r2[1];
      unsigned long long a3 = r3[0] > r3[1] ? r3[0] : r3[1];
      a0 = a0 > a1 ? a0 : a1;
      a2 = a2 > a3 ? a2 : a3;
      const unsigned long long m = a0 > a2 ? a0 : a2;
      const int widx = 8191 - (int)(m & 8191ull);
      const float* cp = src + (size_t)widx * 3;
      cx = cp[0]; cy = cp[1]; cz = cp[2];
    }
    __syncthreads();
    float* o = fa.new_xyz + (size_t)bid * 384;
    if (t < 384) o[t] = nxb[t];
  } else {
    // ------------------------------------------------------ conv GEMMs ---
    const int cb = bid - 128;
    int g, lid;
    if (cb < 196)      { g = 0; lid = cb; }
    else if (cb < 392) { g = 1; lid = cb - 196; }
    else if (cb < 520) { g = 2; lid = cb - 392; }
    else               { g = 3; lid = cb - 520; }
    gemm_tile_t<false>(fa.A[g], fa.W[g], fa.cb[g], fa.sc[g], fa.sh[g],
                       nullptr, nullptr, nullptr, nullptr,
                       fa.H[g], nullptr, 1024, 16, lid >> 2, lid & 3, As, Bs);
  }
}

// --------------------------------------- pos-enc (layer1 fused) GEMM -------
struct PArgs {
  const float *xyz, *w1, *b1, *s1, *t1;   // layer-1 (fused into staging)
  const float *W, *cb, *sc, *sh;          // layer-2
  float* out;
};
__global__ __launch_bounds__(512, 2) void gemm_pe(PArgs pa) {
  __shared__ __align__(16) unsigned short As[128][72];
  __shared__ __align__(16) unsigned short Bs[128][72];
  const int lid = blockIdx.x;
  gemm_tile_t<true>(pa.xyz, pa.W, pa.cb, pa.sc, pa.sh,
                    pa.w1, pa.b1, pa.s1, pa.t1,
                    nullptr, pa.out, 128, 2, lid >> 2, lid & 3, As, Bs);
}

// ------------------------------------------------------- mix + add ---------
// Block = (b, mod). Stage h slab as RAW bf16 (50KB -> 2 blocks/CU) with
// vectorized 16B copies; convert on LDS read. RMW-add onto pos in d_out.
struct MArgs {
  const unsigned short *H0, *H1, *H2, *H3;
  const float *lw0, *lw1, *lw2, *lw3;
  const float *lb0, *lb1, *lb2, *lb3;
  float* out;
};

__global__ __launch_bounds__(512) void mix_add(MArgs ma) {
  __shared__ unsigned short hsb[49 * 512];
  __shared__ float lws[32 * 49];
  __shared__ float lbs[32];
  const int b = blockIdx.x >> 2, mod = blockIdx.x & 3, t = threadIdx.x;
  const unsigned short* H; const float* lw; const float* lb; int L;
  switch (mod) {
    case 0: H = ma.H0; lw = ma.lw0; lb = ma.lb0; L = 49; break;
    case 1: H = ma.H1; lw = ma.lw1; lb = ma.lb1; L = 49; break;
    case 2: H = ma.H2; lw = ma.lw2; lb = ma.lb2; L = 32; break;
    default:H = ma.H3; lw = ma.lw3; lb = ma.lb3; L = 32; break;
  }
  H += (size_t)b * L * 512;
  const int nv = (L * 512) >> 3;           // 16B chunks (8 bf16)
  for (int i = t; i < nv; i += 512)
    *(bf16x8*)&hsb[i << 3] = *(const bf16x8*)&H[i << 3];
  for (int i = t; i < 32 * L; i += 512) lws[i] = lw[i];
  if (t < 32) lbs[t] = lb[t];
  __syncthreads();
  float acc[32];
#pragma unroll
  for (int s = 0; s < 32; ++s) acc[s] = 0.f;
  for (int l = 0; l < L; ++l) {
    const float hv = __uint_as_float(((unsigned)hsb[l * 512 + t]) << 16);
#pragma unroll
    for (int s = 0; s < 32; ++s) acc[s] = fmaf(hv, lws[s * L + l], acc[s]);
  }
  float* O = ma.out + ((size_t)(b * 128 + mod * 32)) * 512 + t;
#pragma unroll
  for (int s = 0; s < 32; ++s) {
    O[(size_t)s * 512] += fmaxf(acc[s] + lbs[s], 0.f);
  }
}

// ---------------------------------------------------------------- launch ---
extern "C" void kernel_launch(void* const* d_in, const int* in_sizes, int n_in,
                              void* d_out, int out_size, void* d_ws, size_t ws_size,
                              hipStream_t stream) {
  const float* rgb    = (const float*)d_in[0];
  const float* depth  = (const float*)d_in[1];
  const float* mmw    = (const float*)d_in[2];
  const float* lidf   = (const float*)d_in[3];
  const float* pts    = (const float*)d_in[4];

  const float* cw[4]  = { (const float*)d_in[5],  (const float*)d_in[11],
                          (const float*)d_in[17], (const float*)d_in[23] };
  const float* cb[4]  = { (const float*)d_in[6],  (const float*)d_in[12],
                          (const float*)d_in[18], (const float*)d_in[24] };
  const float* bns[4] = { (const float*)d_in[7],  (const float*)d_in[13],
                          (const float*)d_in[19], (const float*)d_in[25] };
  const float* bnb[4] = { (const float*)d_in[8],  (const float*)d_in[14],
                          (const float*)d_in[20], (const float*)d_in[26] };
  const float* lw[4]  = { (const float*)d_in[9],  (const float*)d_in[15],
                          (const float*)d_in[21], (const float*)d_in[27] };
  const float* lb[4]  = { (const float*)d_in[10], (const float*)d_in[16],
                          (const float*)d_in[22], (const float*)d_in[28] };

  const float* pe_w1 = (const float*)d_in[29];
  const float* pe_b1 = (const float*)d_in[30];
  const float* pe_s1 = (const float*)d_in[31];
  const float* pe_t1 = (const float*)d_in[32];
  const float* pe_w2 = (const float*)d_in[33];
  const float* pe_b2 = (const float*)d_in[34];
  const float* pe_s2 = (const float*)d_in[35];
  const float* pe_t2 = (const float*)d_in[36];

  char* ws = (char*)d_ws;
  float* new_xyz = (float*)ws;                                   // 49152 f32
  unsigned short* h0 = (unsigned short*)(ws + 196608);           // 6272*512 bf16
  unsigned short* h1 = h0 + (size_t)6272 * 512;
  unsigned short* h2 = h1 + (size_t)6272 * 512;                  // 4096*512
  unsigned short* h3 = h2 + (size_t)4096 * 512;
  float* out = (float*)d_out;

  FArgs fa;
  for (int i = 0; i < 4; ++i) {
    fa.A[i] = (i == 0) ? rgb : (i == 1) ? depth : (i == 2) ? mmw : lidf;
    fa.W[i] = cw[i]; fa.cb[i] = cb[i]; fa.sc[i] = bns[i]; fa.sh[i] = bnb[i];
  }
  fa.H[0] = h0; fa.H[1] = h1; fa.H[2] = h2; fa.H[3] = h3;
  fa.pts = pts; fa.new_xyz = new_xyz;
  fused_main<<<776, 512, 0, stream>>>(fa);

  PArgs pa;
  pa.xyz = new_xyz; pa.w1 = pe_w1; pa.b1 = pe_b1; pa.s1 = pe_s1; pa.t1 = pe_t1;
  pa.W = pe_w2; pa.cb = pe_b2; pa.sc = pe_s2; pa.sh = pe_t2;
  pa.out = out;
  gemm_pe<<<512, 512, 0, stream>>>(pa);

  MArgs ma;
  ma.H0 = h0; ma.H1 = h1; ma.H2 = h2; ma.H3 = h3;
  ma.lw0 = lw[0]; ma.lw1 = lw[1]; ma.lw2 = lw[2]; ma.lw3 = lw[3];
  ma.lb0 = lb[0]; ma.lb1 = lb[1]; ma.lb2 = lb[2]; ma.lb3 = lb[3];
  ma.out = out;
  mix_add<<<512, 512, 0, stream>>>(ma);
}